// Round 11
// baseline (1405.618 us; speedup 1.0000x reference)
//
#include <hip/hip_runtime.h>

#define BB 512
#define SS 256
#define HH 128
#define NC 10

typedef _Float16 v8h __attribute__((ext_vector_type(8)));
typedef float    v4f __attribute__((ext_vector_type(4)));

// barrier WITHOUT the compiler's vmcnt(0) drain: only LDS ordering + sync.
// Global loads/stores in flight deliberately cross this barrier.
__device__ __forceinline__ void barrier_nodrain() {
    asm volatile("s_waitcnt lgkmcnt(0)\n\ts_barrier" ::: "memory");
}

// =====================================================================
// proj_k: out[m][j] = sum_d A[m][d] * W[j][d]  (bias-free; scan adds it)
// Layer 0 only (K=28).
// =====================================================================
template<int K>
__global__ __launch_bounds__(256, 1)
void proj_k(const float* __restrict__ A, const float* __restrict__ W,
            float* __restrict__ out)
{
    constexpr int AS = ((K + 31) / 32) * 32 + 4;
    constexpr int KQ = K / 4;
    constexpr int KCW = (K < 32) ? K : 32;
    constexpr int WQ = KCW / 4;
    const int tid = threadIdx.x;
    const int tx = tid & 15;
    const int ty = tid >> 4;
    const size_t m0 = (size_t)blockIdx.x * 64;

    __shared__ float Arm[64 * AS];
    __shared__ float Wst[128 * 36];

    for (int idx = tid; idx < 64 * KQ; idx += 256) {
        const int row = idx / KQ, kq = idx % KQ;
        const float4 v = *(const float4*)(A + (m0 + row) * K + 4 * kq);
        *(float4*)(&Arm[row * AS + 4 * kq]) = v;
    }

    float acc[4][8];
    #pragma unroll
    for (int c = 0; c < 8; ++c)
        #pragma unroll
        for (int r = 0; r < 4; ++r) acc[r][c] = 0.f;

    #pragma unroll 1
    for (int kc = 0; kc < K; kc += KCW) {
        __syncthreads();
        for (int idx = tid; idx < 128 * WQ; idx += 256) {
            const int col = idx / WQ, q = idx % WQ;
            const float4 v = *(const float4*)(W + (size_t)col * K + kc + 4 * q);
            *(float4*)(&Wst[col * 36 + 4 * q]) = v;
        }
        __syncthreads();
        #pragma unroll 2
        for (int q = 0; q < WQ; ++q) {
            float4 av[4];
            #pragma unroll
            for (int r = 0; r < 4; ++r)
                av[r] = *(const float4*)(&Arm[(ty + 16 * r) * AS + kc + 4 * q]);
            #pragma unroll
            for (int c = 0; c < 8; ++c) {
                const float4 wv = *(const float4*)(&Wst[(tx + 16 * c) * 36 + 4 * q]);
                #pragma unroll
                for (int r = 0; r < 4; ++r)
                    acc[r][c] += av[r].x * wv.x + av[r].y * wv.y
                               + av[r].z * wv.z + av[r].w * wv.w;
            }
        }
    }

    #pragma unroll
    for (int r = 0; r < 4; ++r)
        #pragma unroll
        for (int c = 0; c < 8; ++c)
            out[(m0 + ty + 16 * r) * HH + tx + 16 * c] = acc[r][c];
}

// =====================================================================
// scan_mfma (R11): R10 MFMA recurrence + fused next-layer projection,
// restructured so NO global op drains inside the step loop:
//  - barrier_nodrain() (lgkmcnt only) instead of __syncthreads()
//  - xw staged in 4-step LDS chunks: loads issued at substep 0,
//    deposited at substep 3, consumed from step s4+4 (latency hidden)
//  - proj results batched 4 steps in registers, stored async
// 16 rows/block, 4 waves, 32 blocks. f16 hi/lo split (3-term rec,
// 2-term proj). waves_per_eu(1,1) -> 512-reg budget.
// =====================================================================
template<bool LAST>
__global__ __attribute__((amdgpu_flat_work_group_size(256, 256),
                          amdgpu_waves_per_eu(1, 1)))
void scan_mfma(float* __restrict__ buf, float* __restrict__ hfin,
               const float* __restrict__ w_hh, const float* __restrict__ w_ih,
               const float* __restrict__ b_ih_l, const float* __restrict__ b_hh_l)
{
    const int tid  = threadIdx.x;
    const int w    = tid >> 6;
    const int lane = tid & 63;
    const int l15  = lane & 15;
    const int quad = lane >> 4;
    const int b0   = blockIdx.x * 16;

    __shared__ __align__(16) _Float16 AH[2][2][16][136];   // h ping-pong hi/lo
    __shared__ __align__(16) float    XW[2][4 * 16 * 132]; // xw chunks, pad 132

    {   // zero h_{-1}
        uint32_t* zp = (uint32_t*)&AH[0][0][0][0];
        for (int i = tid; i < (2 * 16 * 136) / 2; i += 256) zp[i] = 0u;
    }

    int coln[2]; float bias[2];
    #pragma unroll
    for (int nt = 0; nt < 2; ++nt) {
        coln[nt] = 32 * w + 16 * nt + l15;
        bias[nt] = b_ih_l[coln[nt]] + b_hh_l[coln[nt]];
    }

    // B fragments: W_hh hi+lo, W_ih hi (B[k][n] = W[n][k])
    v8h bhh[2][4], bhl[2][4], bih[2][4];
    #pragma unroll
    for (int nt = 0; nt < 2; ++nt) {
        #pragma unroll
        for (int kt = 0; kt < 4; ++kt) {
            const float* ph = w_hh + (size_t)coln[nt] * HH + kt * 32 + quad * 8;
            v8h hi, lo;
            #pragma unroll
            for (int i = 0; i < 8; ++i) {
                const float x = ph[i];
                const _Float16 h = (_Float16)x;
                hi[i] = h; lo[i] = (_Float16)(x - (float)h);
            }
            bhh[nt][kt] = hi; bhl[nt][kt] = lo;
            if (!LAST) {
                const float* pi = w_ih + (size_t)coln[nt] * HH + kt * 32 + quad * 8;
                v8h ih;
                #pragma unroll
                for (int i = 0; i < 8; ++i) ih[i] = (_Float16)pi[i];
                bih[nt][kt] = ih;
            }
        }
    }

    // cooperative xw chunk mapping: 64 segments (sl 0..3, row 0..15) x 512B
    int gofs[8], lofs[8];
    #pragma unroll
    for (int i = 0; i < 8; ++i) {
        const int idx = tid + 256 * i;
        const int seg = idx >> 5, lo = idx & 31;
        const int row = seg & 15, sl = seg >> 4;
        gofs[i] = ((b0 + row) * SS + sl) * HH + lo * 4;
        lofs[i] = (sl * 16 + row) * 132 + lo * 4;
    }
    // per-step xw read offsets (add (s&3)*2112)
    int xro[8];
    #pragma unroll
    for (int nt = 0; nt < 2; ++nt)
        #pragma unroll
        for (int q = 0; q < 4; ++q)
            xro[nt * 4 + q] = (quad * 4 + q) * 132 + coln[nt];
    // per-row base offsets for proj stores / hfin
    int rb[8];
    #pragma unroll
    for (int nt = 0; nt < 2; ++nt)
        #pragma unroll
        for (int q = 0; q < 4; ++q)
            rb[nt * 4 + q] = (b0 + quad * 4 + q) * SS * HH + coln[nt];

    {   // preload chunk 0 (slices 0..3)
        #pragma unroll
        for (int i = 0; i < 8; ++i) {
            const float4 v = *(const float4*)(buf + gofs[i]);
            *(float4*)&XW[0][lofs[i]] = v;
        }
    }
    __syncthreads();

    float4 lv[8];        // chunk loads in flight (substep 0 -> 3)
    float pbuf[4][8];    // proj batch (4 slices)

#define SUBSTEP(PH)                                                            \
    {                                                                          \
        const int S = s4 + PH;                                                 \
        constexpr int CUR = PH & 1, NXT = CUR ^ 1;                             \
        if (PH == 0 && s4 + 4 < SS) {                                          \
            _Pragma("unroll")                                                  \
            for (int i = 0; i < 8; ++i)                                        \
                lv[i] = *(const float4*)(buf + gofs[i] + (s4 + 4) * HH);       \
        }                                                                      \
        v8h ah[4], al[4];                                                      \
        _Pragma("unroll")                                                      \
        for (int kt = 0; kt < 4; ++kt) {                                       \
            ah[kt] = *(const v8h*)&AH[CUR][0][l15][kt * 32 + quad * 8];        \
            al[kt] = *(const v8h*)&AH[CUR][1][l15][kt * 32 + quad * 8];        \
        }                                                                      \
        float hv[8];                                                           \
        _Pragma("unroll")                                                      \
        for (int nt = 0; nt < 2; ++nt) {                                       \
            v4f c0 = {0.f,0.f,0.f,0.f}, c1 = {0.f,0.f,0.f,0.f}, c2 = {0.f,0.f,0.f,0.f}; \
            _Pragma("unroll")                                                  \
            for (int kt = 0; kt < 4; ++kt)                                     \
                c0 = __builtin_amdgcn_mfma_f32_16x16x32_f16(ah[kt], bhh[nt][kt], c0, 0, 0, 0); \
            _Pragma("unroll")                                                  \
            for (int kt = 0; kt < 4; ++kt)                                     \
                c1 = __builtin_amdgcn_mfma_f32_16x16x32_f16(al[kt], bhh[nt][kt], c1, 0, 0, 0); \
            _Pragma("unroll")                                                  \
            for (int kt = 0; kt < 4; ++kt)                                     \
                c2 = __builtin_amdgcn_mfma_f32_16x16x32_f16(ah[kt], bhl[nt][kt], c2, 0, 0, 0); \
            const v4f cs = (c0 + c1) + c2;                                     \
            _Pragma("unroll")                                                  \
            for (int q = 0; q < 4; ++q) {                                      \
                const float z = cs[q] + xwb[(S & 3) * 2112 + xro[nt * 4 + q]] + bias[nt]; \
                const float e = __expf(2.f * z);                               \
                hv[nt * 4 + q] = 1.f - 2.f * __builtin_amdgcn_rcpf(1.f + e);   \
            }                                                                  \
        }                                                                      \
        if (!LAST && S > 0) {  /* proj(h_{S-1}) -> pbuf[(S-1)&3] */            \
            _Pragma("unroll")                                                  \
            for (int nt = 0; nt < 2; ++nt) {                                   \
                v4f p0 = {0.f,0.f,0.f,0.f}, p1 = {0.f,0.f,0.f,0.f};            \
                _Pragma("unroll")                                              \
                for (int kt = 0; kt < 4; ++kt) {                               \
                    p0 = __builtin_amdgcn_mfma_f32_16x16x32_f16(ah[kt], bih[nt][kt], p0, 0, 0, 0); \
                    p1 = __builtin_amdgcn_mfma_f32_16x16x32_f16(al[kt], bih[nt][kt], p1, 0, 0, 0); \
                }                                                              \
                const v4f ps = p0 + p1;                                        \
                _Pragma("unroll")                                              \
                for (int q = 0; q < 4; ++q)                                    \
                    pbuf[(PH + 3) & 3][nt * 4 + q] = ps[q];                    \
            }                                                                  \
        }                                                                      \
        if (!LAST && PH == 0 && s4 > 0) {  /* flush slices [s4-4, s4) */       \
            _Pragma("unroll")                                                  \
            for (int sl = 0; sl < 4; ++sl)                                     \
                _Pragma("unroll")                                              \
                for (int i = 0; i < 8; ++i)                                    \
                    buf[rb[i] + (s4 - 4 + sl) * HH] = pbuf[sl][i];             \
        }                                                                      \
        _Pragma("unroll")                                                      \
        for (int nt = 0; nt < 2; ++nt)                                         \
            _Pragma("unroll")                                                  \
            for (int q = 0; q < 4; ++q) {                                      \
                const float x = hv[nt * 4 + q];                                \
                const _Float16 h = (_Float16)x;                                \
                AH[NXT][0][quad * 4 + q][coln[nt]] = h;                        \
                AH[NXT][1][quad * 4 + q][coln[nt]] = (_Float16)(x - (float)h); \
            }                                                                  \
        if (LAST && S == SS - 1) {                                             \
            _Pragma("unroll")                                                  \
            for (int i = 0; i < 8; ++i)                                        \
                hfin[(rb[i] / SS) /*(b0+row)*HH*/ ] = 0.f; /* placeholder */   \
        }                                                                      \
        if (PH == 3 && s4 + 4 < SS) {                                          \
            _Pragma("unroll")                                                  \
            for (int i = 0; i < 8; ++i)                                        \
                *(float4*)&xwn[lofs[i]] = lv[i];                               \
        }                                                                      \
        barrier_nodrain();                                                     \
    }

    // NOTE: the hfin placeholder above is replaced by a correct epilogue
    // store below; disable the in-loop store entirely.
#undef SUBSTEP
#define SUBSTEP(PH)                                                            \
    {                                                                          \
        const int S = s4 + PH;                                                 \
        constexpr int CUR = PH & 1, NXT = CUR ^ 1;                             \
        if (PH == 0 && s4 + 4 < SS) {                                          \
            _Pragma("unroll")                                                  \
            for (int i = 0; i < 8; ++i)                                        \
                lv[i] = *(const float4*)(buf + gofs[i] + (s4 + 4) * HH);       \
        }                                                                      \
        v8h ah[4], al[4];                                                      \
        _Pragma("unroll")                                                      \
        for (int kt = 0; kt < 4; ++kt) {                                       \
            ah[kt] = *(const v8h*)&AH[CUR][0][l15][kt * 32 + quad * 8];        \
            al[kt] = *(const v8h*)&AH[CUR][1][l15][kt * 32 + quad * 8];        \
        }                                                                      \
        float hv[8];                                                           \
        _Pragma("unroll")                                                      \
        for (int nt = 0; nt < 2; ++nt) {                                       \
            v4f c0 = {0.f,0.f,0.f,0.f}, c1 = {0.f,0.f,0.f,0.f}, c2 = {0.f,0.f,0.f,0.f}; \
            _Pragma("unroll")                                                  \
            for (int kt = 0; kt < 4; ++kt)                                     \
                c0 = __builtin_amdgcn_mfma_f32_16x16x32_f16(ah[kt], bhh[nt][kt], c0, 0, 0, 0); \
            _Pragma("unroll")                                                  \
            for (int kt = 0; kt < 4; ++kt)                                     \
                c1 = __builtin_amdgcn_mfma_f32_16x16x32_f16(al[kt], bhh[nt][kt], c1, 0, 0, 0); \
            _Pragma("unroll")                                                  \
            for (int kt = 0; kt < 4; ++kt)                                     \
                c2 = __builtin_amdgcn_mfma_f32_16x16x32_f16(ah[kt], bhl[nt][kt], c2, 0, 0, 0); \
            const v4f cs = (c0 + c1) + c2;                                     \
            _Pragma("unroll")                                                  \
            for (int q = 0; q < 4; ++q) {                                      \
                const float z = cs[q] + xwb[(S & 3) * 2112 + xro[nt * 4 + q]] + bias[nt]; \
                const float e = __expf(2.f * z);                               \
                hv[nt * 4 + q] = 1.f - 2.f * __builtin_amdgcn_rcpf(1.f + e);   \
            }                                                                  \
        }                                                                      \
        if (!LAST && S > 0) {                                                  \
            _Pragma("unroll")                                                  \
            for (int nt = 0; nt < 2; ++nt) {                                   \
                v4f p0 = {0.f,0.f,0.f,0.f}, p1 = {0.f,0.f,0.f,0.f};            \
                _Pragma("unroll")                                              \
                for (int kt = 0; kt < 4; ++kt) {                               \
                    p0 = __builtin_amdgcn_mfma_f32_16x16x32_f16(ah[kt], bih[nt][kt], p0, 0, 0, 0); \
                    p1 = __builtin_amdgcn_mfma_f32_16x16x32_f16(al[kt], bih[nt][kt], p1, 0, 0, 0); \
                }                                                              \
                const v4f ps = p0 + p1;                                        \
                _Pragma("unroll")                                              \
                for (int q = 0; q < 4; ++q)                                    \
                    pbuf[(PH + 3) & 3][nt * 4 + q] = ps[q];                    \
            }                                                                  \
        }                                                                      \
        if (!LAST && PH == 0 && s4 > 0) {                                      \
            _Pragma("unroll")                                                  \
            for (int sl = 0; sl < 4; ++sl)                                     \
                _Pragma("unroll")                                              \
                for (int i = 0; i < 8; ++i)                                    \
                    buf[rb[i] + (s4 - 4 + sl) * HH] = pbuf[sl][i];             \
        }                                                                      \
        _Pragma("unroll")                                                      \
        for (int nt = 0; nt < 2; ++nt)                                         \
            _Pragma("unroll")                                                  \
            for (int q = 0; q < 4; ++q) {                                      \
                const float x = hv[nt * 4 + q];                                \
                const _Float16 h = (_Float16)x;                                \
                AH[NXT][0][quad * 4 + q][coln[nt]] = h;                        \
                AH[NXT][1][quad * 4 + q][coln[nt]] = (_Float16)(x - (float)h); \
            }                                                                  \
        if (LAST && S == SS - 1) {                                             \
            _Pragma("unroll")                                                  \
            for (int nt = 0; nt < 2; ++nt)                                     \
                _Pragma("unroll")                                              \
                for (int q = 0; q < 4; ++q)                                    \
                    hfin[(b0 + quad * 4 + q) * HH + coln[nt]] = hv[nt * 4 + q]; \
        }                                                                      \
        if (PH == 3 && s4 + 4 < SS) {                                          \
            _Pragma("unroll")                                                  \
            for (int i = 0; i < 8; ++i)                                        \
                *(float4*)&xwn[lofs[i]] = lv[i];                               \
        }                                                                      \
        barrier_nodrain();                                                     \
    }

    for (int s4 = 0; s4 < SS; s4 += 4) {
        const int cbi = (s4 >> 2) & 1;
        const float* xwb = XW[cbi];
        float* xwn = XW[cbi ^ 1];
        SUBSTEP(0)
        SUBSTEP(1)
        SUBSTEP(2)
        SUBSTEP(3)
    }
#undef SUBSTEP

    if (!LAST) {   // proj of h_{SS-1} (in AH[0]) + final flush [SS-4, SS)
        v8h ah[4], al[4];
        #pragma unroll
        for (int kt = 0; kt < 4; ++kt) {
            ah[kt] = *(const v8h*)&AH[0][0][l15][kt * 32 + quad * 8];
            al[kt] = *(const v8h*)&AH[0][1][l15][kt * 32 + quad * 8];
        }
        #pragma unroll
        for (int nt = 0; nt < 2; ++nt) {
            v4f p0 = {0.f,0.f,0.f,0.f}, p1 = {0.f,0.f,0.f,0.f};
            #pragma unroll
            for (int kt = 0; kt < 4; ++kt) {
                p0 = __builtin_amdgcn_mfma_f32_16x16x32_f16(ah[kt], bih[nt][kt], p0, 0, 0, 0);
                p1 = __builtin_amdgcn_mfma_f32_16x16x32_f16(al[kt], bih[nt][kt], p1, 0, 0, 0);
            }
            const v4f ps = p0 + p1;
            #pragma unroll
            for (int q = 0; q < 4; ++q)
                pbuf[3][nt * 4 + q] = ps[q];
        }
        #pragma unroll
        for (int sl = 0; sl < 4; ++sl)
            #pragma unroll
            for (int i = 0; i < 8; ++i)
                buf[rb[i] + (SS - 4 + sl) * HH] = pbuf[sl][i];
    }
}

// =====================================================================
__global__ __launch_bounds__(128)
void fc_k(const float* __restrict__ hlast, const float* __restrict__ fc_w,
          const float* __restrict__ fc_b, float* __restrict__ out)
{
    const int b = blockIdx.x;
    const int tid = threadIdx.x;
    __shared__ __align__(16) float h[HH];
    h[tid] = hlast[(size_t)b * HH + tid];
    __syncthreads();
    if (tid < NC) {
        float a = fc_b[tid];
        const float* wr = fc_w + tid * HH;
        #pragma unroll 4
        for (int k = 0; k < HH; ++k) a += h[k] * wr[k];
        out[(size_t)b * NC + tid] = a;
    }
}

extern "C" void kernel_launch(void* const* d_in, const int* in_sizes, int n_in,
                              void* d_out, int out_size, void* d_ws, size_t ws_size,
                              hipStream_t stream) {
    const float* x     = (const float*)d_in[0];   // (512,256,28)
    const float* w_ih0 = (const float*)d_in[1];   // (128,28)
    const float* w_hh0 = (const float*)d_in[2];   // (128,128)
    const float* b_ih0 = (const float*)d_in[3];
    const float* b_hh0 = (const float*)d_in[4];
    const float* w_ih  = (const float*)d_in[5];   // (3,128,128)
    const float* w_hh  = (const float*)d_in[6];   // (3,128,128)
    const float* b_ih  = (const float*)d_in[7];   // (3,128)
    const float* b_hh  = (const float*)d_in[8];
    const float* fc_w  = (const float*)d_in[9];   // (10,128)
    const float* fc_b  = (const float*)d_in[10];
    float* out = (float*)d_out;

    float* buf  = (float*)d_ws;                   // (B,S,H) fp32 = 64 MB
    float* hfin = buf + (size_t)BB * SS * HH;     // (B,H)

    proj_k<28><<<(BB * SS) / 64, 256, 0, stream>>>(x, w_ih0, buf);
    scan_mfma<false><<<32, 256, 0, stream>>>(buf, hfin, w_hh0, w_ih,
                                             b_ih0, b_hh0);
    scan_mfma<false><<<32, 256, 0, stream>>>(buf, hfin, w_hh,
                                             w_ih + (size_t)1 * HH * HH,
                                             b_ih, b_hh);
    scan_mfma<false><<<32, 256, 0, stream>>>(buf, hfin, w_hh + (size_t)1 * HH * HH,
                                             w_ih + (size_t)2 * HH * HH,
                                             b_ih + HH, b_hh + HH);
    scan_mfma<true><<<32, 256, 0, stream>>>(buf, hfin, w_hh + (size_t)2 * HH * HH,
                                            nullptr, b_ih + 2 * HH, b_hh + 2 * HH);
    fc_k<<<BB, 128, 0, stream>>>(hfin, fc_w, fc_b, out);
}

// Round 13
// 1141.274 us; speedup vs baseline: 1.2316x; 1.2316x over previous
//
#include <hip/hip_runtime.h>

#define BB 512
#define SS 256
#define HH 128
#define NC 10

typedef _Float16 v8h __attribute__((ext_vector_type(8)));
typedef float    v4f __attribute__((ext_vector_type(4)));

#define MFMA16(A, B, C) __builtin_amdgcn_mfma_f32_16x16x32_f16(A, B, C, 0, 0, 0)

// =====================================================================
// proj_k: out[m][j] = sum_d A[m][d] * W[j][d]  (bias-free; scan adds it)
// Layer 0 only (K=28). Known good.
// =====================================================================
template<int K>
__global__ __launch_bounds__(256, 1)
void proj_k(const float* __restrict__ A, const float* __restrict__ W,
            float* __restrict__ out)
{
    constexpr int AS = ((K + 31) / 32) * 32 + 4;
    constexpr int KQ = K / 4;
    constexpr int KCW = (K < 32) ? K : 32;
    constexpr int WQ = KCW / 4;
    const int tid = threadIdx.x;
    const int tx = tid & 15;
    const int ty = tid >> 4;
    const size_t m0 = (size_t)blockIdx.x * 64;

    __shared__ float Arm[64 * AS];
    __shared__ float Wst[128 * 36];

    for (int idx = tid; idx < 64 * KQ; idx += 256) {
        const int row = idx / KQ, kq = idx % KQ;
        const float4 v = *(const float4*)(A + (m0 + row) * K + 4 * kq);
        *(float4*)(&Arm[row * AS + 4 * kq]) = v;
    }

    float acc[4][8];
    #pragma unroll
    for (int c = 0; c < 8; ++c)
        #pragma unroll
        for (int r = 0; r < 4; ++r) acc[r][c] = 0.f;

    #pragma unroll 1
    for (int kc = 0; kc < K; kc += KCW) {
        __syncthreads();
        for (int idx = tid; idx < 128 * WQ; idx += 256) {
            const int col = idx / WQ, q = idx % WQ;
            const float4 v = *(const float4*)(W + (size_t)col * K + kc + 4 * q);
            *(float4*)(&Wst[col * 36 + 4 * q]) = v;
        }
        __syncthreads();
        #pragma unroll 2
        for (int q = 0; q < WQ; ++q) {
            float4 av[4];
            #pragma unroll
            for (int r = 0; r < 4; ++r)
                av[r] = *(const float4*)(&Arm[(ty + 16 * r) * AS + kc + 4 * q]);
            #pragma unroll
            for (int c = 0; c < 8; ++c) {
                const float4 wv = *(const float4*)(&Wst[(tx + 16 * c) * 36 + 4 * q]);
                #pragma unroll
                for (int r = 0; r < 4; ++r)
                    acc[r][c] += av[r].x * wv.x + av[r].y * wv.y
                               + av[r].z * wv.z + av[r].w * wv.w;
            }
        }
    }

    #pragma unroll
    for (int r = 0; r < 4; ++r)
        #pragma unroll
        for (int c = 0; c < 8; ++c)
            out[(m0 + ty + 16 * r) * HH + tx + 16 * c] = acc[r][c];
}

// =====================================================================
// scan_mfma (R13 = R12 with the pbuf race fixed): MFMA recurrence with
// all global traffic batched so most barriers carry no vmcnt drain:
//   substep 0: burst-load xw chunk [s8+4,s8+8) -> xw1 regs
//   substep 1: flush proj slices [s8-4,s8)   BEFORE proj compute
//              (slot 3 filled at substep 0; substep 1's proj would
//               overwrite slot 0 -- this ordering is the race fix)
//   substep 4: burst-load xw chunk [s8+8,s8+12) -> xw0
//   substep 5: flush proj slices [s8,s8+4)   BEFORE proj compute
// MFMA in depth-2 chains (6 rec + 4 proj). f16 hi/lo split.
// 16 rows/block, 4 waves, 32 blocks, waves_per_eu(1,1).
// In-place: slice X loaded at iter X-8/X-4, stored at iter X/X+4.
// =====================================================================
template<bool LAST>
__global__ __attribute__((amdgpu_flat_work_group_size(256, 256),
                          amdgpu_waves_per_eu(1, 1)))
void scan_mfma(float* __restrict__ buf, float* __restrict__ hfin,
               const float* __restrict__ w_hh, const float* __restrict__ w_ih,
               const float* __restrict__ b_ih_l, const float* __restrict__ b_hh_l)
{
    const int tid  = threadIdx.x;
    const int w    = tid >> 6;
    const int lane = tid & 63;
    const int l15  = lane & 15;
    const int quad = lane >> 4;
    const int b0   = blockIdx.x * 16;

    __shared__ __align__(16) _Float16 AH[2][2][16 * 136];   // h ping-pong hi/lo

    {   // zero h_{-1} (AH[0], hi+lo)
        uint32_t* zp = (uint32_t*)&AH[0][0][0];
        for (int i = tid; i < (2 * 16 * 136) / 2; i += 256) zp[i] = 0u;
    }

    int coln[2]; float bias[2];
    #pragma unroll
    for (int nt = 0; nt < 2; ++nt) {
        coln[nt] = 32 * w + 16 * nt + l15;
        bias[nt] = b_ih_l[coln[nt]] + b_hh_l[coln[nt]];
    }

    // B fragments (B[k][n] = W[n][k]): W_hh hi+lo, W_ih hi
    v8h bhh[2][4], bhl[2][4], bih[2][4];
    #pragma unroll
    for (int nt = 0; nt < 2; ++nt) {
        #pragma unroll
        for (int kt = 0; kt < 4; ++kt) {
            const float* ph = w_hh + (size_t)coln[nt] * HH + kt * 32 + quad * 8;
            v8h hi, lo;
            #pragma unroll
            for (int i = 0; i < 8; ++i) {
                const float x = ph[i];
                const _Float16 h = (_Float16)x;
                hi[i] = h; lo[i] = (_Float16)(x - (float)h);
            }
            bhh[nt][kt] = hi; bhl[nt][kt] = lo;
            if (!LAST) {
                const float* pi = w_ih + (size_t)coln[nt] * HH + kt * 32 + quad * 8;
                v8h ih;
                #pragma unroll
                for (int i = 0; i < 8; ++i) ih[i] = (_Float16)pi[i];
                bih[nt][kt] = ih;
            }
        }
    }

    // global scalar index for value (nt,q): row b0+quad*4+q, col coln[nt]
    int rb[8];
    #pragma unroll
    for (int nt = 0; nt < 2; ++nt)
        #pragma unroll
        for (int q = 0; q < 4; ++q)
            rb[nt * 4 + q] = ((b0 + quad * 4 + q) * SS) * HH + coln[nt];

    float xw0[4][8], xw1[4][8];   // 4-step xw chunks (register-resident)
    float pbuf[4][8];             // proj batch (4 slices)

    #pragma unroll
    for (int st = 0; st < 4; ++st)        // preload chunk [0,4)
        #pragma unroll
        for (int i = 0; i < 8; ++i)
            xw0[st][i] = buf[rb[i] + (size_t)st * HH];

    __syncthreads();

#define BURSTLD(DST, BASE)                                                     \
    _Pragma("unroll")                                                          \
    for (int st = 0; st < 4; ++st)                                             \
        _Pragma("unroll")                                                      \
        for (int i = 0; i < 8; ++i)                                            \
            DST[st][i] = buf[rb[i] + (size_t)((BASE) + st) * HH];

#define SUBSTEP(S_, XWB)                                                       \
    {                                                                          \
        constexpr int CUR = (S_) & 1, NXT = CUR ^ 1, PH = (S_) & 3;            \
        const int S = s8 + (S_);                                               \
        if ((S_) == 0 && s8 + 4 < SS) { BURSTLD(xw1, s8 + 4) }                 \
        if ((S_) == 4 && s8 + 8 < SS) { BURSTLD(xw0, s8 + 8) }                 \
        /* flushes BEFORE this substep's proj (race fix, see header) */        \
        if (!LAST && (S_) == 1 && s8 > 0) {                                    \
            _Pragma("unroll")                                                  \
            for (int sl = 0; sl < 4; ++sl)                                     \
                _Pragma("unroll")                                              \
                for (int i = 0; i < 8; ++i)                                    \
                    buf[rb[i] + (size_t)(s8 - 4 + sl) * HH] = pbuf[sl][i];     \
        }                                                                      \
        if (!LAST && (S_) == 5) {                                              \
            _Pragma("unroll")                                                  \
            for (int sl = 0; sl < 4; ++sl)                                     \
                _Pragma("unroll")                                              \
                for (int i = 0; i < 8; ++i)                                    \
                    buf[rb[i] + (size_t)(s8 + sl) * HH] = pbuf[sl][i];         \
        }                                                                      \
        v8h ah[4], al[4];                                                      \
        _Pragma("unroll")                                                      \
        for (int kt = 0; kt < 4; ++kt) {                                       \
            ah[kt] = *(const v8h*)&AH[CUR][0][l15 * 136 + kt * 32 + quad * 8]; \
            al[kt] = *(const v8h*)&AH[CUR][1][l15 * 136 + kt * 32 + quad * 8]; \
        }                                                                      \
        float hv[8];                                                           \
        _Pragma("unroll")                                                      \
        for (int nt = 0; nt < 2; ++nt) {                                       \
            v4f c0 = {0.f, 0.f, 0.f, 0.f};                                     \
            v4f c1 = c0, c2 = c0, c3 = c0, c4 = c0, c5 = c0;                   \
            c0 = MFMA16(ah[0], bhh[nt][0], c0);                                \
            c0 = MFMA16(ah[1], bhh[nt][1], c0);                                \
            c1 = MFMA16(ah[2], bhh[nt][2], c1);                                \
            c1 = MFMA16(ah[3], bhh[nt][3], c1);                                \
            c2 = MFMA16(al[0], bhh[nt][0], c2);                                \
            c2 = MFMA16(al[1], bhh[nt][1], c2);                                \
            c3 = MFMA16(al[2], bhh[nt][2], c3);                                \
            c3 = MFMA16(al[3], bhh[nt][3], c3);                                \
            c4 = MFMA16(ah[0], bhl[nt][0], c4);                                \
            c4 = MFMA16(ah[1], bhl[nt][1], c4);                                \
            c5 = MFMA16(ah[2], bhl[nt][2], c5);                                \
            c5 = MFMA16(ah[3], bhl[nt][3], c5);                                \
            const v4f cs = ((c0 + c1) + (c2 + c3)) + (c4 + c5);                \
            _Pragma("unroll")                                                  \
            for (int q = 0; q < 4; ++q) {                                      \
                const float z = cs[q] + XWB[PH][nt * 4 + q] + bias[nt];        \
                const float e = __expf(2.f * z);                               \
                hv[nt * 4 + q] = 1.f - 2.f * __builtin_amdgcn_rcpf(1.f + e);   \
            }                                                                  \
        }                                                                      \
        if (!LAST && ((S_) > 0 || s8 > 0)) {  /* proj(h_{S-1}) -> slot (S-1)&3 */ \
            _Pragma("unroll")                                                  \
            for (int nt = 0; nt < 2; ++nt) {                                   \
                v4f p0 = {0.f, 0.f, 0.f, 0.f};                                 \
                v4f p1 = p0, p2 = p0, p3 = p0;                                 \
                p0 = MFMA16(ah[0], bih[nt][0], p0);                            \
                p0 = MFMA16(ah[1], bih[nt][1], p0);                            \
                p1 = MFMA16(ah[2], bih[nt][2], p1);                            \
                p1 = MFMA16(ah[3], bih[nt][3], p1);                            \
                p2 = MFMA16(al[0], bih[nt][0], p2);                            \
                p2 = MFMA16(al[1], bih[nt][1], p2);                            \
                p3 = MFMA16(al[2], bih[nt][2], p3);                            \
                p3 = MFMA16(al[3], bih[nt][3], p3);                            \
                const v4f ps = (p0 + p1) + (p2 + p3);                          \
                _Pragma("unroll")                                              \
                for (int q = 0; q < 4; ++q)                                    \
                    pbuf[((S_) + 3) & 3][nt * 4 + q] = ps[q];                  \
            }                                                                  \
        }                                                                      \
        _Pragma("unroll")                                                      \
        for (int nt = 0; nt < 2; ++nt)                                         \
            _Pragma("unroll")                                                  \
            for (int q = 0; q < 4; ++q) {                                      \
                const float x = hv[nt * 4 + q];                                \
                const _Float16 hc = (_Float16)x;                               \
                AH[NXT][0][(quad * 4 + q) * 136 + coln[nt]] = hc;              \
                AH[NXT][1][(quad * 4 + q) * 136 + coln[nt]] =                  \
                    (_Float16)(x - (float)hc);                                 \
            }                                                                  \
        if (LAST && S == SS - 1) {                                             \
            _Pragma("unroll")                                                  \
            for (int nt = 0; nt < 2; ++nt)                                     \
                _Pragma("unroll")                                              \
                for (int q = 0; q < 4; ++q)                                    \
                    hfin[(b0 + quad * 4 + q) * HH + coln[nt]] = hv[nt * 4 + q];\
        }                                                                      \
        __syncthreads();                                                       \
    }

    for (int s8 = 0; s8 < SS; s8 += 8) {
        SUBSTEP(0, xw0) SUBSTEP(1, xw0) SUBSTEP(2, xw0) SUBSTEP(3, xw0)
        SUBSTEP(4, xw1) SUBSTEP(5, xw1) SUBSTEP(6, xw1) SUBSTEP(7, xw1)
    }
#undef SUBSTEP
#undef BURSTLD

    if (!LAST) {   // proj of h_{SS-1} (in AH[0]) + final flush [SS-4, SS)
        // pbuf slots 0..2 hold slices 252..254 (substeps 5,6,7 of s8=248)
        v8h ah[4], al[4];
        #pragma unroll
        for (int kt = 0; kt < 4; ++kt) {
            ah[kt] = *(const v8h*)&AH[0][0][l15 * 136 + kt * 32 + quad * 8];
            al[kt] = *(const v8h*)&AH[0][1][l15 * 136 + kt * 32 + quad * 8];
        }
        #pragma unroll
        for (int nt = 0; nt < 2; ++nt) {
            v4f p0 = {0.f, 0.f, 0.f, 0.f};
            v4f p1 = p0, p2 = p0, p3 = p0;
            p0 = MFMA16(ah[0], bih[nt][0], p0);
            p0 = MFMA16(ah[1], bih[nt][1], p0);
            p1 = MFMA16(ah[2], bih[nt][2], p1);
            p1 = MFMA16(ah[3], bih[nt][3], p1);
            p2 = MFMA16(al[0], bih[nt][0], p2);
            p2 = MFMA16(al[1], bih[nt][1], p2);
            p3 = MFMA16(al[2], bih[nt][2], p3);
            p3 = MFMA16(al[3], bih[nt][3], p3);
            const v4f ps = (p0 + p1) + (p2 + p3);
            #pragma unroll
            for (int q = 0; q < 4; ++q)
                pbuf[3][nt * 4 + q] = ps[q];
        }
        #pragma unroll
        for (int sl = 0; sl < 4; ++sl)
            #pragma unroll
            for (int i = 0; i < 8; ++i)
                buf[rb[i] + (size_t)(SS - 4 + sl) * HH] = pbuf[sl][i];
    }
}

// =====================================================================
__global__ __launch_bounds__(128)
void fc_k(const float* __restrict__ hlast, const float* __restrict__ fc_w,
          const float* __restrict__ fc_b, float* __restrict__ out)
{
    const int b = blockIdx.x;
    const int tid = threadIdx.x;
    __shared__ __align__(16) float h[HH];
    h[tid] = hlast[(size_t)b * HH + tid];
    __syncthreads();
    if (tid < NC) {
        float a = fc_b[tid];
        const float* wr = fc_w + tid * HH;
        #pragma unroll 4
        for (int k = 0; k < HH; ++k) a += h[k] * wr[k];
        out[(size_t)b * NC + tid] = a;
    }
}

extern "C" void kernel_launch(void* const* d_in, const int* in_sizes, int n_in,
                              void* d_out, int out_size, void* d_ws, size_t ws_size,
                              hipStream_t stream) {
    const float* x     = (const float*)d_in[0];   // (512,256,28)
    const float* w_ih0 = (const float*)d_in[1];   // (128,28)
    const float* w_hh0 = (const float*)d_in[2];   // (128,128)
    const float* b_ih0 = (const float*)d_in[3];
    const float* b_hh0 = (const float*)d_in[4];
    const float* w_ih  = (const float*)d_in[5];   // (3,128,128)
    const float* w_hh  = (const float*)d_in[6];   // (3,128,128)
    const float* b_ih  = (const float*)d_in[7];   // (3,128)
    const float* b_hh  = (const float*)d_in[8];
    const float* fc_w  = (const float*)d_in[9];   // (10,128)
    const float* fc_b  = (const float*)d_in[10];
    float* out = (float*)d_out;

    float* buf  = (float*)d_ws;                   // (B,S,H) fp32 = 64 MB
    float* hfin = buf + (size_t)BB * SS * HH;     // (B,H)

    proj_k<28><<<(BB * SS) / 64, 256, 0, stream>>>(x, w_ih0, buf);
    scan_mfma<false><<<32, 256, 0, stream>>>(buf, hfin, w_hh0, w_ih,
                                             b_ih0, b_hh0);
    scan_mfma<false><<<32, 256, 0, stream>>>(buf, hfin, w_hh,
                                             w_ih + (size_t)1 * HH * HH,
                                             b_ih, b_hh);
    scan_mfma<false><<<32, 256, 0, stream>>>(buf, hfin, w_hh + (size_t)1 * HH * HH,
                                             w_ih + (size_t)2 * HH * HH,
                                             b_ih + HH, b_hh + HH);
    scan_mfma<true><<<32, 256, 0, stream>>>(buf, hfin, w_hh + (size_t)2 * HH * HH,
                                            nullptr, b_ih + 2 * HH, b_hh + 2 * HH);
    fc_k<<<BB, 128, 0, stream>>>(hfin, fc_w, fc_b, out);
}

// Round 14
// 755.704 us; speedup vs baseline: 1.8600x; 1.5102x over previous
//
#include <hip/hip_runtime.h>

#define BB 512
#define SS 256
#define HH 128
#define NC 10

typedef float v2f __attribute__((ext_vector_type(2)));
typedef _Float16 v8h __attribute__((ext_vector_type(8)));
typedef float    v4f __attribute__((ext_vector_type(4)));

#define MFMA16(A, B, C) __builtin_amdgcn_mfma_f32_16x16x32_f16(A, B, C, 0, 0, 0)

// acc + (give from lane selected by DPP ctrl)
template<int CTRL>
__device__ __forceinline__ float dppadd(float acc, float give) {
    int t = __builtin_amdgcn_update_dpp(0, __float_as_int(give), CTRL, 0xF, 0xF, true);
    return acc + __int_as_float(t);
}

// =====================================================================
// proj_k: out[m][j] = b1[j] + b2[j] + sum_d A[m][d] * W[j][d]
// VALU path, layer 0 only (K=28). Known good (R8).
// =====================================================================
template<int K>
__global__ __launch_bounds__(256, 1)
void proj_k(const float* __restrict__ A, const float* __restrict__ W,
            const float* __restrict__ b1, const float* __restrict__ b2,
            float* __restrict__ out)
{
    constexpr int AS = ((K + 31) / 32) * 32 + 4;
    constexpr int KQ = K / 4;
    constexpr int KCW = (K < 32) ? K : 32;
    constexpr int WQ = KCW / 4;
    const int tid = threadIdx.x;
    const int tx = tid & 15;
    const int ty = tid >> 4;
    const size_t m0 = (size_t)blockIdx.x * 64;

    __shared__ float Arm[64 * AS];
    __shared__ float Wst[128 * 36];

    for (int idx = tid; idx < 64 * KQ; idx += 256) {
        const int row = idx / KQ, kq = idx % KQ;
        const float4 v = *(const float4*)(A + (m0 + row) * K + 4 * kq);
        *(float4*)(&Arm[row * AS + 4 * kq]) = v;
    }

    float acc[4][8];
    #pragma unroll
    for (int c = 0; c < 8; ++c) {
        const int j = tx + 16 * c;
        const float bj = b1[j] + b2[j];
        #pragma unroll
        for (int r = 0; r < 4; ++r) acc[r][c] = bj;
    }

    #pragma unroll 1
    for (int kc = 0; kc < K; kc += KCW) {
        __syncthreads();
        for (int idx = tid; idx < 128 * WQ; idx += 256) {
            const int col = idx / WQ, q = idx % WQ;
            const float4 v = *(const float4*)(W + (size_t)col * K + kc + 4 * q);
            *(float4*)(&Wst[col * 36 + 4 * q]) = v;
        }
        __syncthreads();
        #pragma unroll 2
        for (int q = 0; q < WQ; ++q) {
            float4 av[4];
            #pragma unroll
            for (int r = 0; r < 4; ++r)
                av[r] = *(const float4*)(&Arm[(ty + 16 * r) * AS + kc + 4 * q]);
            #pragma unroll
            for (int c = 0; c < 8; ++c) {
                const float4 wv = *(const float4*)(&Wst[(tx + 16 * c) * 36 + 4 * q]);
                #pragma unroll
                for (int r = 0; r < 4; ++r)
                    acc[r][c] += av[r].x * wv.x + av[r].y * wv.y
                               + av[r].z * wv.z + av[r].w * wv.w;
            }
        }
    }

    #pragma unroll
    for (int r = 0; r < 4; ++r)
        #pragma unroll
        for (int c = 0; c < 8; ++c)
            out[(m0 + ty + 16 * r) * HH + tx + 16 * c] = acc[r][c];
}

// =====================================================================
// mfma_proj (R14): out[m][j] = b1[j]+b2[j] + sum_d A[m][d]*W[j][d]
// One-shot f16 MFMA GEMM, M=BB*SS, N=K=128. Embarrassingly parallel:
// 2048 blocks x 4 waves; wave owns 16 rows x all 128 cols. No LDS, no
// barriers. 2-term split (A hi/lo x B hi) — same numerics R10 verified.
// Fragment layouts (16x16x32): A[m=l15][k=quad*8+j]; B[k][n=l15] =
// W[n][k]; C: col=l15, row=quad*4+reg  (R10-verified).
// In-place safe (A==out): wave reads its 16 rows fully before storing.
// =====================================================================
__global__ __attribute__((amdgpu_flat_work_group_size(256, 256),
                          amdgpu_waves_per_eu(1, 1)))
void mfma_proj(const float* __restrict__ A, const float* __restrict__ W,
               const float* __restrict__ b1, const float* __restrict__ b2,
               float* __restrict__ out)
{
    const int tid  = threadIdx.x;
    const int wv   = tid >> 6;
    const int lane = tid & 63;
    const int l15  = lane & 15;
    const int quad = lane >> 4;
    const size_t m0 = (size_t)blockIdx.x * 64 + wv * 16;

    // A fragments (rows m0+l15), hi/lo split
    v8h ah[4], al[4];
    #pragma unroll
    for (int kt = 0; kt < 4; ++kt) {
        const float* pa = A + (m0 + l15) * HH + kt * 32 + quad * 8;
        const float4 f0 = *(const float4*)pa;
        const float4 f1 = *(const float4*)(pa + 4);
        const float av[8] = {f0.x, f0.y, f0.z, f0.w, f1.x, f1.y, f1.z, f1.w};
        v8h hi, lo;
        #pragma unroll
        for (int i = 0; i < 8; ++i) {
            const _Float16 h = (_Float16)av[i];
            hi[i] = h; lo[i] = (_Float16)(av[i] - (float)h);
        }
        ah[kt] = hi; al[kt] = lo;
    }

    // B fragments: W hi only (8 n-tiles x 4 k-tiles)
    v8h bw[8][4];
    #pragma unroll
    for (int nt = 0; nt < 8; ++nt)
        #pragma unroll
        for (int kt = 0; kt < 4; ++kt) {
            const float* pw = W + (size_t)(16 * nt + l15) * HH + kt * 32 + quad * 8;
            const float4 f0 = *(const float4*)pw;
            const float4 f1 = *(const float4*)(pw + 4);
            const float wvv[8] = {f0.x, f0.y, f0.z, f0.w, f1.x, f1.y, f1.z, f1.w};
            v8h hi;
            #pragma unroll
            for (int i = 0; i < 8; ++i) hi[i] = (_Float16)wvv[i];
            bw[nt][kt] = hi;
        }

    #pragma unroll
    for (int nt = 0; nt < 8; ++nt) {
        const int j = 16 * nt + l15;
        const float bias = b1[j] + b2[j];
        v4f c = {bias, bias, bias, bias};
        #pragma unroll
        for (int kt = 0; kt < 4; ++kt)
            c = MFMA16(ah[kt], bw[nt][kt], c);
        #pragma unroll
        for (int kt = 0; kt < 4; ++kt)
            c = MFMA16(al[kt], bw[nt][kt], c);
        #pragma unroll
        for (int q = 0; q < 4; ++q)
            out[(m0 + quad * 4 + q) * HH + j] = c[q];
    }
}

// =====================================================================
// scan_k (R8, verbatim — proven 122 us/layer): 256 thr/row; j=tid>>4
// (16 col-groups of 8), r=tid&15 (k-chunk [8r,8r+8)). Weight-slot
// permutation -> cndmask-free DPP reduce-scatter. One barrier/step.
// =====================================================================
template<bool WRITE_ALL>
__global__ __attribute__((amdgpu_flat_work_group_size(256, 256),
                          amdgpu_waves_per_eu(2, 2)))
void scan_k(float* __restrict__ buf, float* __restrict__ hfin,
            const float* __restrict__ w_hh)
{
    const int b   = blockIdx.x;
    const int tid = threadIdx.x;
    const int j   = tid >> 4;
    const int r   = tid & 15;
    const int g7  = r & 7;

    float* const row = buf + (size_t)b * SS * HH;

    v2f w2[8][4];
    #pragma unroll
    for (int i = 0; i < 8; ++i) {
        const v2f* wr = (const v2f*)(w_hh + (size_t)(8 * j + (i ^ g7)) * HH + 8 * r);
        w2[i][0] = wr[0]; w2[i][1] = wr[1]; w2[i][2] = wr[2]; w2[i][3] = wr[3];
    }

    __shared__ float hsw[2][192];
    __shared__ float xwl[2][8][HH];

    if (tid < 192) hsw[0][tid] = 0.f;
    const int t   = tid >> 5;
    const int pos = (tid & 31) * 4;
    {
        const float4 v = *(const float4*)(row + (size_t)t * HH + pos);
        *(float4*)(&xwl[0][t][pos]) = v;
    }
    __syncthreads();

    const int cc  = 8 * j + g7;
    const int wsw = 12 * j + g7;

    int cur = 0;
    for (int s = 0; s < SS; ++s) {
        const int ph = s & 7, cb = (s >> 3) & 1;
        const bool do_stage = (ph == 0) && (s + 8 < SS);
        float4 stg;
        if (do_stage)
            stg = *(const float4*)(row + (size_t)(s + 8 + t) * HH + pos);
        if (WRITE_ALL && s > 0 && tid < 32) {
            const float4 hv = *(const float4*)(&hsw[cur][12 * (tid >> 1) + 4 * (tid & 1)]);
            *(float4*)(row + (size_t)(s - 1) * HH + 4 * tid) = hv;
        }
        const float myxw = xwl[cb][ph][cc];

        const v2f* hb = (const v2f*)&hsw[cur][12 * r];
        const v2f hp0 = hb[0], hp1 = hb[1], hp2 = hb[2], hp3 = hb[3];
        float v[8];
        #pragma unroll
        for (int i = 0; i < 8; ++i) {
            v2f a = hp0 * w2[i][0];
            a += hp1 * w2[i][1];
            a += hp2 * w2[i][2];
            a += hp3 * w2[i][3];
            v[i] = a.x + a.y;
        }

        float s0 = dppadd<0xB1>(v[0], v[1]);
        float s2 = dppadd<0xB1>(v[2], v[3]);
        float s4 = dppadd<0xB1>(v[4], v[5]);
        float s6 = dppadd<0xB1>(v[6], v[7]);
        s0 = dppadd<0x4E>(s0, s2);
        s4 = dppadd<0x4E>(s4, s6);
        {
            int t1 = __builtin_amdgcn_update_dpp(0, __float_as_int(s4), 0x124, 0xF, 0xF, true);
            int t2 = __builtin_amdgcn_update_dpp(0, __float_as_int(s4), 0x12C, 0xF, 0xF, true);
            s0 += __int_as_float((r & 4) ? t2 : t1);
        }
        s0 = dppadd<0x128>(s0, s0);

        const float z = s0 + myxw;
        const float e = __expf(2.f * z);
        const float hnew = 1.f - 2.f * __builtin_amdgcn_rcpf(1.f + e);

        if (r < 8) hsw[cur ^ 1][wsw] = hnew;
        if (do_stage) *(float4*)(&xwl[cb ^ 1][t][pos]) = stg;
        __syncthreads();
        cur ^= 1;
    }

    if (tid < 32) {
        const float4 hv = *(const float4*)(&hsw[cur][12 * (tid >> 1) + 4 * (tid & 1)]);
        if (WRITE_ALL) *(float4*)(row + (size_t)(SS - 1) * HH + 4 * tid) = hv;
        else           *(float4*)(hfin + (size_t)b * HH + 4 * tid) = hv;
    }
}

// =====================================================================
__global__ __launch_bounds__(128)
void fc_k(const float* __restrict__ hlast, const float* __restrict__ fc_w,
          const float* __restrict__ fc_b, float* __restrict__ out)
{
    const int b = blockIdx.x;
    const int tid = threadIdx.x;
    __shared__ __align__(16) float h[HH];
    h[tid] = hlast[(size_t)b * HH + tid];
    __syncthreads();
    if (tid < NC) {
        float a = fc_b[tid];
        const float* wr = fc_w + tid * HH;
        #pragma unroll 4
        for (int k = 0; k < HH; ++k) a += h[k] * wr[k];
        out[(size_t)b * NC + tid] = a;
    }
}

extern "C" void kernel_launch(void* const* d_in, const int* in_sizes, int n_in,
                              void* d_out, int out_size, void* d_ws, size_t ws_size,
                              hipStream_t stream) {
    const float* x     = (const float*)d_in[0];   // (512,256,28)
    const float* w_ih0 = (const float*)d_in[1];   // (128,28)
    const float* w_hh0 = (const float*)d_in[2];   // (128,128)
    const float* b_ih0 = (const float*)d_in[3];
    const float* b_hh0 = (const float*)d_in[4];
    const float* w_ih  = (const float*)d_in[5];   // (3,128,128)
    const float* w_hh  = (const float*)d_in[6];   // (3,128,128)
    const float* b_ih  = (const float*)d_in[7];   // (3,128)
    const float* b_hh  = (const float*)d_in[8];
    const float* fc_w  = (const float*)d_in[9];   // (10,128)
    const float* fc_b  = (const float*)d_in[10];
    float* out = (float*)d_out;

    float* buf  = (float*)d_ws;                   // (B,S,H) fp32 = 64 MB
    float* hfin = buf + (size_t)BB * SS * HH;     // (B,H)

    // layer 0: VALU proj (K=28, with bias) + scan
    proj_k<28><<<(BB * SS) / 64, 256, 0, stream>>>(x, w_ih0, b_ih0, b_hh0, buf);
    scan_k<true><<<BB, 256, 0, stream>>>(buf, hfin, w_hh0);
    // layers 1..3: full-chip MFMA proj (with bias) + scan
    for (int l = 0; l < 3; ++l) {
        mfma_proj<<<(BB * SS) / 64, 256, 0, stream>>>(
            buf, w_ih + (size_t)l * HH * HH,
            b_ih + (size_t)l * HH, b_hh + (size_t)l * HH, buf);
        if (l < 2) scan_k<true ><<<BB, 256, 0, stream>>>(buf, hfin, w_hh + (size_t)l * HH * HH);
        else       scan_k<false><<<BB, 256, 0, stream>>>(buf, hfin, w_hh + (size_t)l * HH * HH);
    }
    fc_k<<<BB, 128, 0, stream>>>(hfin, fc_w, fc_b, out);
}